// Round 1
// baseline (2427.899 us; speedup 1.0000x reference)
//
#include <hip/hip_runtime.h>
#include <math.h>

#define TPB  256
#define TILE 2048
#define MAXT 2048
#define MAXK 1024

// ---------------------------------------------------------------------------
// Kernel 1: build 64-bit stable-descending sort keys.
// key_f = score + log(mask); map f32 -> ascending-orderable u32, invert for
// descending, pack candidate index in low 32 bits for stable tie-break.
// ---------------------------------------------------------------------------
__global__ void build_keys_kernel(const float* __restrict__ scores,
                                  const float* __restrict__ mask,
                                  unsigned long long* __restrict__ keys,
                                  int N) {
    int i = blockIdx.x * blockDim.x + threadIdx.x;
    if (i >= N) return;
    float key = scores[i] + logf(mask[i]);   // mask==1 -> +0.0 (exact)
    unsigned u = __float_as_uint(key);
    u = (u & 0x80000000u) ? ~u : (u | 0x80000000u);  // ascending-orderable
    u = ~u;                                          // descending order
    keys[i] = ((unsigned long long)u << 32) | (unsigned)i;
}

// ---------------------------------------------------------------------------
// Kernel 2: O(N^2) rank-by-counting sort (round-0 simplicity; all keys are
// distinct because the index is embedded). order[rank(i)] = i.
// Tile keys through LDS; every lane reads the same tile word -> LDS broadcast.
// 4 accumulators break the serial add chain.
// ---------------------------------------------------------------------------
__global__ void rank_scatter_kernel(const unsigned long long* __restrict__ keys,
                                    int* __restrict__ order, int N) {
    __shared__ unsigned long long tile[TILE];
    int i = blockIdx.x * blockDim.x + threadIdx.x;
    unsigned long long Ki = (i < N) ? keys[i] : ~0ull;
    int r0 = 0, r1 = 0, r2 = 0, r3 = 0;
    for (int base = 0; base < N; base += TILE) {
        int tlen = min(TILE, N - base);
        __syncthreads();
        for (int j = threadIdx.x; j < tlen; j += blockDim.x)
            tile[j] = keys[base + j];
        __syncthreads();
        int jj = 0;
        for (; jj + 4 <= tlen; jj += 4) {
            r0 += (tile[jj]     < Ki);
            r1 += (tile[jj + 1] < Ki);
            r2 += (tile[jj + 2] < Ki);
            r3 += (tile[jj + 3] < Ki);
        }
        for (; jj < tlen; jj++) r0 += (tile[jj] < Ki);
    }
    if (i < N) order[r0 + r1 + r2 + r3] = i;
}

// ---------------------------------------------------------------------------
// Kernel 3: single-wave sequential greedy selection + epilogue.
//  - s2e/e2s tables live in LDS (T <= 2048).
//  - candidates prefetched 64 ahead (order + spans) into LDS.
//  - crossing check: width <= 63 handled by one __any over the wave
//    (general loop for wider spans).
//  - early break once cnt == k (state frozen afterwards; matches reference).
//  - accepted list re-sorted by ((s*T+e) << 32 | cand) via in-LDS bitonic
//    (stable tie-break by candidate index == jnp stable argsort).
//  - outputs written as f32: scores | idx | spans(row-major) | valid.
// ---------------------------------------------------------------------------
__global__ void __launch_bounds__(64) greedy_kernel(
    const int* __restrict__ spans,
    const float* __restrict__ scores,
    const int* __restrict__ order,
    const int* __restrict__ tnum_p,
    const int* __restrict__ keep_p,
    float* __restrict__ out,
    int N) {
    __shared__ int s2e[MAXT];
    __shared__ int e2s[MAXT];
    __shared__ unsigned long long acc[MAXK];
    __shared__ int sbuf[64], ebuf[64], cbuf[64];

    const int lane = threadIdx.x;
    const int T  = tnum_p[0];
    const int k0 = keep_p[0];
    const int k  = (k0 < MAXK) ? k0 : MAXK;

    for (int t = lane; t < T && t < MAXT; t += 64) { s2e[t] = -1; e2s[t] = -1; }
    __syncthreads();

    int cnt = 0;
    for (int c0 = 0; c0 < N && cnt < k; c0 += 64) {
        int nb = (N - c0 < 64) ? (N - c0) : 64;
        if (lane < nb) {
            int cand = order[c0 + lane];
            cbuf[lane] = cand;
            sbuf[lane] = spans[2 * cand];
            ebuf[lane] = spans[2 * cand + 1];
        }
        __syncthreads();
        for (int q = 0; q < nb && cnt < k; q++) {
            int s = sbuf[q], e = ebuf[q];
            int w = e - s;                      // tokens to check on each side
            bool crossing = false;
            for (int base = 0; base < w; base += 64) {
                int off = base + lane;
                bool pred = false;
                if (off < w) {
                    // cross1: t in (s, e] with s2e[t] > e
                    pred = (s2e[s + 1 + off] > e);
                    // cross2: t in [s, e) with 0 <= e2s[t] < s
                    int v = e2s[s + off];
                    pred = pred || ((v >= 0) && (v < s));
                }
                if (__any(pred)) { crossing = true; break; }
            }
            if (!crossing) {
                if (lane == 0) {
                    if (e > s2e[s]) s2e[s] = e;
                    int cur = e2s[e];
                    if (cur == -1 || s < cur) e2s[e] = s;
                    acc[cnt] = ((unsigned long long)(unsigned)(s * T + e) << 32)
                             | (unsigned)cbuf[q];
                }
                cnt++;
                __syncthreads();   // uniform: crossing & cnt are wave-uniform
            }
        }
        __syncthreads();
    }

    // ---- bitonic ascending sort of acc[0..M), pad with +inf keys ----
    int M = 2;
    while (M < cnt) M <<= 1;       // cnt <= k <= MAXK
    for (int j = lane; j < M; j += 64)
        if (j >= cnt) acc[j] = ~0ull;
    __syncthreads();
    for (int kk = 2; kk <= M; kk <<= 1) {
        for (int j = kk >> 1; j > 0; j >>= 1) {
            for (int i2 = lane; i2 < M; i2 += 64) {
                int ixj = i2 ^ j;
                if (ixj > i2) {
                    unsigned long long a = acc[i2], b = acc[ixj];
                    bool up = ((i2 & kk) == 0);
                    if ((a > b) == up) { acc[i2] = b; acc[ixj] = a; }
                }
            }
            __syncthreads();
        }
    }

    // ---- epilogue: write all 5*k0 output elements as f32 ----
    for (int j = lane; j < k0; j += 64) {
        if (j < cnt) {
            int cand = (int)(acc[j] & 0xFFFFFFFFu);
            out[j]                  = scores[cand];
            out[k0 + j]             = (float)cand;
            out[2 * k0 + 2 * j]     = (float)spans[2 * cand];
            out[2 * k0 + 2 * j + 1] = (float)spans[2 * cand + 1];
            out[4 * k0 + j]         = 1.0f;
        } else {
            out[j]                  = 0.0f;
            out[k0 + j]             = 0.0f;
            out[2 * k0 + 2 * j]     = 0.0f;
            out[2 * k0 + 2 * j + 1] = 0.0f;
            out[4 * k0 + j]         = 0.0f;
        }
    }
}

extern "C" void kernel_launch(void* const* d_in, const int* in_sizes, int n_in,
                              void* d_out, int out_size, void* d_ws, size_t ws_size,
                              hipStream_t stream) {
    const int*   spans  = (const int*)d_in[0];
    const float* scores = (const float*)d_in[1];
    const float* mask   = (const float*)d_in[2];
    const int*   tnum   = (const int*)d_in[3];
    const int*   keep   = (const int*)d_in[4];
    const int N = in_sizes[1];   // number of spans (scores element count)

    // workspace layout: keys[N] u64, then order[N] i32  (~737 KB total)
    unsigned long long* keys = (unsigned long long*)d_ws;
    int* order = (int*)((char*)d_ws + (size_t)N * sizeof(unsigned long long));
    float* out = (float*)d_out;

    int blocks = (N + TPB - 1) / TPB;
    build_keys_kernel<<<blocks, TPB, 0, stream>>>(scores, mask, keys, N);
    rank_scatter_kernel<<<blocks, TPB, 0, stream>>>(keys, order, N);
    greedy_kernel<<<1, 64, 0, stream>>>(spans, scores, order, tnum, keep, out, N);
}

// Round 2
// 859.797 us; speedup vs baseline: 2.8238x; 2.8238x over previous
//
#include <hip/hip_runtime.h>
#include <math.h>
#include <limits.h>

#define TPB  256
#define MAXT 2048
#define TPAD 64          // LDS pad so unconditional reads past e stay in-bounds
#define MAXK 1024

// ---------------------------------------------------------------------------
// Kernel 1: build 32-bit stable-descending sort keys + index payload.
// key_f = score + log(mask); map f32 -> ascending-orderable u32, invert for
// descending. Stability of LSD radix gives index tie-break (== jnp.argsort).
// ---------------------------------------------------------------------------
__global__ void build_keys_kernel(const float* __restrict__ scores,
                                  const float* __restrict__ mask,
                                  unsigned* __restrict__ keys,
                                  int* __restrict__ idx, int N) {
    int i = blockIdx.x * blockDim.x + threadIdx.x;
    if (i >= N) return;
    float key = scores[i] + logf(mask[i]);   // mask==1 -> +0.0 (exact)
    unsigned u = __float_as_uint(key);
    u = (u & 0x80000000u) ? ~u : (u | 0x80000000u);  // ascending-orderable
    keys[i] = ~u;                                    // descending order
    idx[i] = i;
}

// ---------------------------------------------------------------------------
// Radix pass kernels: 8-bit digits, digit-major histogram [256][nb].
// ---------------------------------------------------------------------------
__global__ void radix_hist(const unsigned* __restrict__ keys,
                           unsigned* __restrict__ hist, int N, int shift) {
    __shared__ unsigned h[256];
    h[threadIdx.x] = 0;
    __syncthreads();
    int i = blockIdx.x * blockDim.x + threadIdx.x;
    if (i < N) atomicAdd(&h[(keys[i] >> shift) & 255u], 1u);
    __syncthreads();
    hist[threadIdx.x * gridDim.x + blockIdx.x] = h[threadIdx.x];
}

// exclusive scan over flattened [digit][block]: two-phase (row sums, 256-wide
// block scan, then serial row writes) -> only 8 barriers total.
__global__ void radix_scan(unsigned* __restrict__ hist, int nb) {
    __shared__ unsigned bufA[256], bufB[256];
    int d = threadIdx.x;
    unsigned sum = 0;
    for (int b = 0; b < nb; ++b) sum += hist[d * nb + b];
    bufA[d] = sum;
    __syncthreads();
    unsigned* src = bufA; unsigned* dst = bufB;
    for (int off = 1; off < 256; off <<= 1) {
        dst[d] = src[d] + ((d >= off) ? src[d - off] : 0u);
        __syncthreads();
        unsigned* t = src; src = dst; dst = t;
    }
    unsigned run = src[d] - sum;          // exclusive prefix of digit totals
    for (int b = 0; b < nb; ++b) {
        unsigned v = hist[d * nb + b];
        hist[d * nb + b] = run;
        run += v;
    }
}

__global__ void radix_scatter(const unsigned* __restrict__ keys_in,
                              const int* __restrict__ idx_in,
                              unsigned* __restrict__ keys_out,
                              int* __restrict__ idx_out,
                              const unsigned* __restrict__ offsets,
                              int N, int shift) {
    __shared__ unsigned char dig[256];
    __shared__ unsigned boff[256];
    int tid = threadIdx.x;
    int i = blockIdx.x * blockDim.x + tid;
    boff[tid] = offsets[tid * gridDim.x + blockIdx.x];
    unsigned key = 0; int pay = 0; unsigned d = 0;
    bool v = (i < N);
    if (v) {
        key = keys_in[i];
        pay = idx_in[i];
        d = (key >> shift) & 255u;
        dig[tid] = (unsigned char)d;
    }
    __syncthreads();
    if (v) {
        int rank = 0;
        for (int j = 0; j < tid; ++j) rank += (dig[j] == (unsigned char)d);
        unsigned pos = boff[d] + (unsigned)rank;
        keys_out[pos] = key;
        idx_out[pos] = pay;
    }
}

// ---------------------------------------------------------------------------
// Kernel 3: single-wave batched-speculative greedy.
// Monotonicity: s2e only grows, e2s only shrinks -> a candidate rejected vs an
// older table state stays rejected. So 64 lanes pre-check 64 candidates in
// parallel vs the current tables; survivors are resolved serially in-register
// (pairwise crossing vs batch-accepted via shfl+ballot); accepted spans then
// update tables with parallel LDS atomics.
// ---------------------------------------------------------------------------
__global__ void __launch_bounds__(64) greedy_kernel(
    const int2* __restrict__ spans2,
    const int* __restrict__ spans,
    const float* __restrict__ scores,
    const int* __restrict__ order,
    const int* __restrict__ tnum_p,
    const int* __restrict__ keep_p,
    float* __restrict__ out,
    int N) {
    __shared__ int s2e[MAXT + TPAD];
    __shared__ int e2s[MAXT + TPAD];
    __shared__ unsigned long long acc[MAXK];

    const int lane = threadIdx.x;
    const int T  = tnum_p[0];
    const int k0 = keep_p[0];
    const int k  = (k0 < MAXK) ? k0 : MAXK;

    for (int t = lane; t < MAXT + TPAD; t += 64) {
        s2e[t] = -1;          // never > e
        e2s[t] = INT_MAX;     // never < s  (sentinel replaces reference's -1)
    }
    __syncthreads();

    // two-deep prefetch: cc/cs/ce = current batch; nc = order idx, next batch
    int cc = -1, cs = 0, ce = 0, nc = -1;
    if (lane < N) cc = order[lane];
    if (64 + lane < N) nc = order[64 + lane];
    if (cc >= 0) { int2 sp = spans2[cc]; cs = sp.x; ce = sp.y; }

    int cnt = 0;
    for (int c0 = 0; c0 < N && cnt < k; c0 += 64) {
        // issue prefetch: spans for next batch, order for batch after next
        int pc = nc, ps = 0, pe = 0;
        if (pc >= 0) { int2 sp = spans2[pc]; ps = sp.x; pe = sp.y; }
        int i2 = c0 + 128 + lane;
        nc = (i2 < N) ? order[i2] : -1;

        // ---- parallel pre-check vs current tables ----
        bool ok = (cc >= 0);
        int w = ce - cs;
        int wmax = w;
        for (int m = 32; m; m >>= 1) {
            int o = __shfl_xor(wmax, m);
            wmax = (o > wmax) ? o : wmax;
        }
        bool crossed = false;
        for (int off = 0; off < wmax; ++off) {
            // cross1: t in (s,e] with s2e[t] > e ; cross2: t in [s,e) e2s[t] < s
            bool c1 = (s2e[cs + 1 + off] > ce);
            bool c2 = (e2s[cs + off] < cs);
            crossed |= (off < w) & (c1 | c2);
        }
        ok = ok && !crossed;

        // ---- serial resolution over survivors (registers only) ----
        unsigned long long pre = __ballot(ok);
        unsigned long long accm = 0;
        while (pre && cnt < k) {
            int q = __ffsll((long long)pre) - 1;
            pre &= pre - 1;
            int sq = __shfl(cs, q);
            int eq = __shfl(ce, q);
            bool cr = false;
            if ((accm >> lane) & 1ull) {
                // does accepted (cs,ce) make candidate (sq,eq) crossing?
                cr = (sq < cs && cs <= eq && ce > eq) ||
                     (sq <= ce && ce < eq && cs < sq);
            }
            if (__ballot(cr) == 0ull) {
                accm |= 1ull << q;
                if (lane == q)
                    acc[cnt] = ((unsigned long long)(unsigned)(cs * T + ce) << 32)
                             | (unsigned)cc;
                cnt++;
            }
        }

        // ---- apply accepted updates (parallel LDS atomics) ----
        if ((accm >> lane) & 1ull) {
            atomicMax(&s2e[cs], ce);
            atomicMin(&e2s[ce], cs);
        }
        __syncthreads();

        // rotate prefetch registers
        cc = pc; cs = ps; ce = pe;
    }

    // ---- bitonic ascending sort of acc[0..cnt), pad with +inf keys ----
    int M = 2;
    while (M < cnt) M <<= 1;
    for (int j = lane; j < M; j += 64)
        if (j >= cnt) acc[j] = ~0ull;
    __syncthreads();
    for (int kk = 2; kk <= M; kk <<= 1) {
        for (int j = kk >> 1; j > 0; j >>= 1) {
            for (int i2 = lane; i2 < M; i2 += 64) {
                int ixj = i2 ^ j;
                if (ixj > i2) {
                    unsigned long long a = acc[i2], b = acc[ixj];
                    bool up = ((i2 & kk) == 0);
                    if ((a > b) == up) { acc[i2] = b; acc[ixj] = a; }
                }
            }
            __syncthreads();
        }
    }

    // ---- epilogue: scores | idx | spans | valid, all f32 ----
    for (int j = lane; j < k0; j += 64) {
        if (j < cnt) {
            int cand = (int)(acc[j] & 0xFFFFFFFFu);
            out[j]                  = scores[cand];
            out[k0 + j]             = (float)cand;
            out[2 * k0 + 2 * j]     = (float)spans[2 * cand];
            out[2 * k0 + 2 * j + 1] = (float)spans[2 * cand + 1];
            out[4 * k0 + j]         = 1.0f;
        } else {
            out[j]                  = 0.0f;
            out[k0 + j]             = 0.0f;
            out[2 * k0 + 2 * j]     = 0.0f;
            out[2 * k0 + 2 * j + 1] = 0.0f;
            out[4 * k0 + j]         = 0.0f;
        }
    }
}

extern "C" void kernel_launch(void* const* d_in, const int* in_sizes, int n_in,
                              void* d_out, int out_size, void* d_ws, size_t ws_size,
                              hipStream_t stream) {
    const int*   spans  = (const int*)d_in[0];
    const float* scores = (const float*)d_in[1];
    const float* mask   = (const float*)d_in[2];
    const int*   tnum   = (const int*)d_in[3];
    const int*   keep   = (const int*)d_in[4];
    const int N = in_sizes[1];

    const int nb = (N + TPB - 1) / TPB;

    // workspace: keysA[N] keysB[N] (u32), idxA[N] idxB[N] (i32), hist[256*nb]
    char* p = (char*)d_ws;
    unsigned* keysA = (unsigned*)p;            p += (size_t)N * 4;
    unsigned* keysB = (unsigned*)p;            p += (size_t)N * 4;
    int*      idxA  = (int*)p;                 p += (size_t)N * 4;
    int*      idxB  = (int*)p;                 p += (size_t)N * 4;
    unsigned* hist  = (unsigned*)p;            // 256*nb*4 bytes

    float* out = (float*)d_out;

    build_keys_kernel<<<nb, TPB, 0, stream>>>(scores, mask, keysA, idxA, N);

    // 4 stable LSD passes: A->B->A->B->A (final order in idxA)
    unsigned* ka = keysA; int* ia = idxA;
    unsigned* kb = keysB; int* ib = idxB;
    for (int pass = 0; pass < 4; ++pass) {
        int shift = pass * 8;
        radix_hist<<<nb, TPB, 0, stream>>>(ka, hist, N, shift);
        radix_scan<<<1, 256, 0, stream>>>(hist, nb);
        radix_scatter<<<nb, TPB, 0, stream>>>(ka, ia, kb, ib, hist, N, shift);
        unsigned* tk = ka; ka = kb; kb = tk;
        int* ti = ia; ia = ib; ib = ti;
    }

    greedy_kernel<<<1, 64, 0, stream>>>((const int2*)spans, spans, scores,
                                        ia, tnum, keep, out, N);
}

// Round 3
// 835.790 us; speedup vs baseline: 2.9049x; 1.0287x over previous
//
#include <hip/hip_runtime.h>
#include <math.h>
#include <limits.h>

#define TPB  256
#define MAXT 2048
#define TPAD 64          // pad so unconditional reads past e stay in-bounds
#define MAXK 1024
#define MAXW 32          // fast-path width; wider spans use fallback loop

// ---------------------------------------------------------------------------
// Kernel 1: build 32-bit stable-descending sort keys + index payload, and
// the pass-0 block histogram (fused). hist layout: [digit][block].
// ---------------------------------------------------------------------------
__global__ void build_keys_hist(const float* __restrict__ scores,
                                const float* __restrict__ mask,
                                unsigned* __restrict__ keys,
                                int* __restrict__ idx,
                                unsigned* __restrict__ hist0, int N) {
    __shared__ unsigned h[256];
    int tid = threadIdx.x;
    h[tid] = 0;
    __syncthreads();
    int i = blockIdx.x * blockDim.x + tid;
    if (i < N) {
        float key = scores[i] + logf(mask[i]);   // mask==1 -> +0.0 (exact)
        unsigned u = __float_as_uint(key);
        u = (u & 0x80000000u) ? ~u : (u | 0x80000000u);  // ascending-orderable
        u = ~u;                                          // descending order
        keys[i] = u;
        idx[i] = i;
        atomicAdd(&h[u & 255u], 1u);
    }
    __syncthreads();
    hist0[tid * gridDim.x + blockIdx.x] = h[tid];   // full overwrite, no prezero
}

// ---------------------------------------------------------------------------
// Exclusive scan over flattened [digit][block] (unchanged from round 2).
// ---------------------------------------------------------------------------
__global__ void radix_scan(unsigned* __restrict__ hist, int nb) {
    __shared__ unsigned bufA[256], bufB[256];
    int d = threadIdx.x;
    unsigned sum = 0;
    for (int b = 0; b < nb; ++b) sum += hist[d * nb + b];
    bufA[d] = sum;
    __syncthreads();
    unsigned* src = bufA; unsigned* dst = bufB;
    for (int off = 1; off < 256; off <<= 1) {
        dst[d] = src[d] + ((d >= off) ? src[d - off] : 0u);
        __syncthreads();
        unsigned* t = src; src = dst; dst = t;
    }
    unsigned run = src[d] - sum;          // exclusive prefix of digit totals
    for (int b = 0; b < nb; ++b) {
        unsigned v = hist[d * nb + b];
        hist[d * nb + b] = run;
        run += v;
    }
}

// ---------------------------------------------------------------------------
// Scatter with ballot-based stable ranking + fused next-pass histogram.
// Rank within wave: 8 bit-serial ballots -> same-digit lane mask.
// Cross-wave offsets: per-wave per-digit counts in LDS, scanned by thread=digit.
// ---------------------------------------------------------------------------
__global__ void radix_scatter2(const unsigned* __restrict__ keys_in,
                               const int* __restrict__ idx_in,
                               unsigned* __restrict__ keys_out,
                               int* __restrict__ idx_out,
                               const unsigned* __restrict__ offsets,
                               unsigned* __restrict__ hist_next,
                               int N, int shift, int next_shift) {
    __shared__ unsigned wcnt[4][256];   // [wave][digit]
    __shared__ unsigned boff[256];
    int tid = threadIdx.x;
    int wave = tid >> 6, lane = tid & 63;
    int nb = gridDim.x;

    wcnt[0][tid] = 0; wcnt[1][tid] = 0; wcnt[2][tid] = 0; wcnt[3][tid] = 0;
    boff[tid] = offsets[tid * nb + blockIdx.x];

    int i = blockIdx.x * blockDim.x + tid;
    bool v = (i < N);
    unsigned key = 0; int pay = 0; unsigned d = 0;
    if (v) { key = keys_in[i]; pay = idx_in[i]; d = (key >> shift) & 255u; }

    unsigned long long vmask = __ballot(v);
    unsigned long long m = vmask;
    #pragma unroll
    for (int b = 0; b < 8; ++b) {
        unsigned long long bb = __ballot((d >> b) & 1u);
        m &= ((d >> b) & 1u) ? bb : ~bb;
    }
    unsigned long long lt = (lane == 63) ? ~0ull >> 1 : ((1ull << lane) - 1ull);
    // note: (1ull<<63)-1 is fine too; guard avoids UB paranoia for lane 63
    lt = (1ull << lane) - 1ull;   // lane<64, shift of 63 max: defined
    int rank = __popcll(m & lt);
    if (v && rank == 0) wcnt[wave][d] = (unsigned)__popcll(m);  // leader writes
    __syncthreads();
    // thread 'tid' scans digit 'tid' across 4 waves (exclusive)
    unsigned run = 0;
    #pragma unroll
    for (int w = 0; w < 4; ++w) {
        unsigned c = wcnt[w][tid];
        wcnt[w][tid] = run;
        run += c;
    }
    __syncthreads();
    if (v) {
        unsigned pos = boff[d] + wcnt[wave][d] + (unsigned)rank;
        keys_out[pos] = key;
        idx_out[pos] = pay;
        if (hist_next)
            atomicAdd(&hist_next[((key >> next_shift) & 255u) * nb + (pos >> 8)], 1u);
    }
}

// ---------------------------------------------------------------------------
// Kernel 3: single-wave batched-speculative greedy.
// Tables interleaved as int2 tab[t] = (s2e[t], e2s[t]); pre-check is a fully
// unrolled 33-deep ds_read_b64 sequence (loads issue back-to-back, one wait)
// instead of 29 serial latency round-trips.
// ---------------------------------------------------------------------------
__global__ void __launch_bounds__(64) greedy_kernel(
    const int2* __restrict__ spans2,
    const int* __restrict__ spans,
    const float* __restrict__ scores,
    const int* __restrict__ order,
    const int* __restrict__ tnum_p,
    const int* __restrict__ keep_p,
    float* __restrict__ out,
    int N) {
    __shared__ int2 tab[MAXT + TPAD];   // .x = s2e (grows), .y = e2s (shrinks)
    __shared__ unsigned long long acc[MAXK];

    const int lane = threadIdx.x;
    const int T  = tnum_p[0];
    const int k0 = keep_p[0];
    const int k  = (k0 < MAXK) ? k0 : MAXK;

    for (int t = lane; t < MAXT + TPAD; t += 64)
        tab[t] = make_int2(-1, INT_MAX);   // never > e / never < s
    __syncthreads();

    // two-deep prefetch: cc/cs/ce = current batch; nc = order idx, next batch
    int cc = -1, cs = 0, ce = 0, nc = -1;
    if (lane < N) cc = order[lane];
    if (64 + lane < N) nc = order[64 + lane];
    if (cc >= 0) { int2 sp = spans2[cc]; cs = sp.x; ce = sp.y; }

    int cnt = 0;
    for (int c0 = 0; c0 < N && cnt < k; c0 += 64) {
        // issue prefetch: spans for next batch, order for batch after next
        int pc = nc, ps = 0, pe = 0;
        if (pc >= 0) { int2 sp = spans2[pc]; ps = sp.x; pe = sp.y; }
        int i2 = c0 + 128 + lane;
        nc = (i2 < N) ? order[i2] : -1;

        // ---- parallel pre-check vs current tables (pipelined loads) ----
        // cross1: off in [1, w]:   tab[s+off].x > e
        // cross2: off in [0, w-1]: tab[s+off].y < s
        int w = ce - cs;
        bool crossed = false;
        #pragma unroll
        for (int off = 0; off <= MAXW; ++off) {
            int2 tv = tab[cs + off];
            bool c1 = (off >= 1) & (off <= w) & (tv.x > ce);
            bool c2 = (off < w) & (tv.y < cs);
            crossed |= c1 | c2;
        }
        if (__any(w > MAXW)) {              // general fallback (rare/never)
            for (int off = MAXW + 1; off <= w; ++off) {
                int2 tv = tab[cs + off];
                crossed |= ((off < w) & (tv.y < cs)) | (tv.x > ce);
            }
        }
        bool ok = (cc >= 0) && !crossed;

        // ---- serial resolution over survivors (registers only) ----
        unsigned long long pre = __ballot(ok);
        unsigned long long accm = 0;
        while (pre && cnt < k) {
            int q = __ffsll((long long)pre) - 1;
            pre &= pre - 1;
            int sq = __shfl(cs, q);
            int eq = __shfl(ce, q);
            bool cr = false;
            if ((accm >> lane) & 1ull) {
                // does batch-accepted (cs,ce) make candidate (sq,eq) crossing?
                cr = (sq < cs && cs <= eq && ce > eq) ||
                     (sq <= ce && ce < eq && cs < sq);
            }
            if (__ballot(cr) == 0ull) {
                accm |= 1ull << q;
                if (lane == q)
                    acc[cnt] = ((unsigned long long)(unsigned)(cs * T + ce) << 32)
                             | (unsigned)cc;
                cnt++;
            }
        }

        // ---- apply accepted updates (parallel LDS atomics) ----
        if ((accm >> lane) & 1ull) {
            atomicMax(&tab[cs].x, ce);
            atomicMin(&tab[ce].y, cs);
        }
        __syncthreads();

        // rotate prefetch registers
        cc = pc; cs = ps; ce = pe;
    }

    // ---- bitonic ascending sort of acc[0..cnt), pad with +inf keys ----
    int M = 2;
    while (M < cnt) M <<= 1;
    for (int j = lane; j < M; j += 64)
        if (j >= cnt) acc[j] = ~0ull;
    __syncthreads();
    for (int kk = 2; kk <= M; kk <<= 1) {
        for (int j = kk >> 1; j > 0; j >>= 1) {
            for (int i2 = lane; i2 < M; i2 += 64) {
                int ixj = i2 ^ j;
                if (ixj > i2) {
                    unsigned long long a = acc[i2], b = acc[ixj];
                    bool up = ((i2 & kk) == 0);
                    if ((a > b) == up) { acc[i2] = b; acc[ixj] = a; }
                }
            }
            __syncthreads();
        }
    }

    // ---- epilogue: scores | idx | spans | valid, all f32 ----
    for (int j = lane; j < k0; j += 64) {
        if (j < cnt) {
            int cand = (int)(acc[j] & 0xFFFFFFFFu);
            out[j]                  = scores[cand];
            out[k0 + j]             = (float)cand;
            out[2 * k0 + 2 * j]     = (float)spans[2 * cand];
            out[2 * k0 + 2 * j + 1] = (float)spans[2 * cand + 1];
            out[4 * k0 + j]         = 1.0f;
        } else {
            out[j]                  = 0.0f;
            out[k0 + j]             = 0.0f;
            out[2 * k0 + 2 * j]     = 0.0f;
            out[2 * k0 + 2 * j + 1] = 0.0f;
            out[4 * k0 + j]         = 0.0f;
        }
    }
}

extern "C" void kernel_launch(void* const* d_in, const int* in_sizes, int n_in,
                              void* d_out, int out_size, void* d_ws, size_t ws_size,
                              hipStream_t stream) {
    const int*   spans  = (const int*)d_in[0];
    const float* scores = (const float*)d_in[1];
    const float* mask   = (const float*)d_in[2];
    const int*   tnum   = (const int*)d_in[3];
    const int*   keep   = (const int*)d_in[4];
    const int N = in_sizes[1];

    const int nb = (N + TPB - 1) / TPB;
    const size_t histSz = (size_t)256 * nb;

    // ws: keysA[N] keysB[N] idxA[N] idxB[N] hist[4][256*nb]
    char* p = (char*)d_ws;
    unsigned* keysA = (unsigned*)p;            p += (size_t)N * 4;
    unsigned* keysB = (unsigned*)p;            p += (size_t)N * 4;
    int*      idxA  = (int*)p;                 p += (size_t)N * 4;
    int*      idxB  = (int*)p;                 p += (size_t)N * 4;
    unsigned* hist  = (unsigned*)p;            // 4 * histSz entries

    float* out = (float*)d_out;

    // zero hists 1..3 (accumulated via global atomics during scatter passes)
    hipMemsetAsync(hist + histSz, 0, 3 * histSz * sizeof(unsigned), stream);

    build_keys_hist<<<nb, TPB, 0, stream>>>(scores, mask, keysA, idxA, hist, N);

    unsigned* ka = keysA; int* ia = idxA;
    unsigned* kb = keysB; int* ib = idxB;
    for (int pass = 0; pass < 4; ++pass) {
        unsigned* hcur  = hist + (size_t)pass * histSz;
        unsigned* hnext = (pass < 3) ? hist + (size_t)(pass + 1) * histSz : nullptr;
        radix_scan<<<1, 256, 0, stream>>>(hcur, nb);
        radix_scatter2<<<nb, TPB, 0, stream>>>(ka, ia, kb, ib, hcur, hnext,
                                               N, pass * 8, (pass + 1) * 8);
        unsigned* tk = ka; ka = kb; kb = tk;
        int* ti = ia; ia = ib; ib = ti;
    }

    greedy_kernel<<<1, 64, 0, stream>>>((const int2*)spans, spans, scores,
                                        ia, tnum, keep, out, N);
}

// Round 4
// 373.535 us; speedup vs baseline: 6.4998x; 2.2375x over previous
//
#include <hip/hip_runtime.h>
#include <math.h>
#include <limits.h>

#define TPB   256
#define TILE  1024          // items per block-tile (256 thr x 4 rounds)
#define RNDS  4
#define MAXT  2048
#define TPAD  64            // pad so unconditional reads past e stay in-bounds
#define MAXK  1024
#define MAXW  29            // max span width in this problem (W=30 -> w<=29)

// Shared memory union: phases are separated by barriers.
struct SMem {
  union {
    unsigned h[4 * 256];                  // P0: 4 pass histograms
    struct {                              // radix pass phases
      unsigned wcnt[4][256];              // [wave][digit] (also scan scratch)
      unsigned runCnt[256];
      unsigned baseL[256];
    } pass;
    struct {                              // greedy phase (block 0)
      unsigned tabP[MAXT + TPAD];         // packed: hi16=e2s(enc), lo16=s2e+1
      int2     tab[MAXT + TPAD];          // authoritative: .x=s2e, .y=e2s
      unsigned long long acc[MAXK];
      unsigned long long surv[TPB];       // packed s<<48|e<<32|cand
      unsigned gsp[64];
      int wvs[4];
      int gcnt;
    } g;
  };
};

// Device-scope grid barrier. SAFE because grid (<=60 blocks, 256 thr) is
// fully co-resident on 256 CUs. ctr[] zeroed by memset node each launch.
__device__ inline void gbar(unsigned* ctr, int idx, unsigned nblk) {
  __syncthreads();
  if (threadIdx.x == 0) {
    __threadfence();                          // release: flush my L2 writes
    atomicAdd(&ctr[idx], 1u);
    while (atomicAdd(&ctr[idx], 0u) < nblk) { __builtin_amdgcn_s_sleep(8); }
    __threadfence();                          // acquire: invalidate stale
  }
  __syncthreads();
}

__global__ void mega_kernel(
    const int2* __restrict__ spans2, const int* __restrict__ spans,
    const float* __restrict__ scores, const float* __restrict__ mask,
    const int* __restrict__ tnum_p, const int* __restrict__ keep_p,
    float* __restrict__ out, int N, int nT,
    unsigned* ctr, unsigned* ghist, unsigned* tileCnt,
    unsigned* keysA, unsigned* keysB, int* idxA, int* idxB) {
  __shared__ SMem s;
  const int tid = threadIdx.x;
  const int lane = tid & 63;
  const int wave = tid >> 6;

  // ------------------ P0: build keys + all 4 histograms --------------------
  {
    for (int j = tid; j < 1024; j += TPB) s.h[j] = 0;
    __syncthreads();
    const int tile0 = blockIdx.x * TILE;
    for (int r = 0; r < RNDS; ++r) {
      int i = tile0 + r * 256 + tid;
      if (i < N) {
        float kf = scores[i] + logf(mask[i]);          // mask==1 -> +0 exact
        unsigned u = __float_as_uint(kf);
        u = (u & 0x80000000u) ? ~u : (u | 0x80000000u);
        u = ~u;                                        // descending order
        keysA[i] = u;
        atomicAdd(&s.h[(u & 255u)], 1u);
        atomicAdd(&s.h[256 + ((u >> 8) & 255u)], 1u);
        atomicAdd(&s.h[512 + ((u >> 16) & 255u)], 1u);
        atomicAdd(&s.h[768 + (u >> 24)], 1u);
      }
    }
    __syncthreads();
    for (int j = tid; j < 1024; j += TPB)
      if (s.h[j]) atomicAdd(&ghist[j], s.h[j]);
  }
  gbar(ctr, 0, nT);

  // ------------------ P1: block 0 scans digit bases (4x256) ----------------
  if (blockIdx.x == 0) {
    for (int p = 0; p < 4; ++p) {
      unsigned v = ghist[p * 256 + tid];
      unsigned* A = s.pass.wcnt[0];
      unsigned* B = s.pass.wcnt[1];
      A[tid] = v;
      __syncthreads();
      for (int off = 1; off < 256; off <<= 1) {
        B[tid] = A[tid] + ((tid >= off) ? A[tid - off] : 0u);
        __syncthreads();
        unsigned* t = A; A = B; B = t;
      }
      ghist[p * 256 + tid] = A[tid] - v;   // exclusive
      __syncthreads();
    }
  }
  gbar(ctr, 1, nT);

  // ------------------ 4 fused rank/scatter radix passes --------------------
  for (int p = 0; p < 4; ++p) {
    const unsigned* srck = (p & 1) ? keysB : keysA;
    const int*      srci = (p & 1) ? idxB : idxA;     // p==0: payload = i
    unsigned*       dstk = (p & 1) ? keysA : keysB;
    int*            dsti = (p & 1) ? idxA : idxB;
    const int shift = 8 * p;
    const int tile0 = blockIdx.x * TILE;

    s.pass.runCnt[tid] = 0;
    unsigned mykey[RNDS]; int mypay[RNDS]; unsigned mypos[RNDS]; bool myval[RNDS];
    #pragma unroll
    for (int r = 0; r < RNDS; ++r) {
      __syncthreads();
      s.pass.wcnt[0][tid] = 0; s.pass.wcnt[1][tid] = 0;
      s.pass.wcnt[2][tid] = 0; s.pass.wcnt[3][tid] = 0;
      __syncthreads();
      int i = tile0 + r * 256 + tid;
      bool v = (i < N);
      unsigned key = v ? srck[i] : 0u;
      int pay = v ? ((p == 0) ? i : srci[i]) : 0;
      unsigned d = (key >> shift) & 255u;
      unsigned long long mm = __ballot(v);     // stable rank within wave
      #pragma unroll
      for (int b = 0; b < 8; ++b) {
        unsigned long long bb = __ballot((d >> b) & 1u);
        mm &= ((d >> b) & 1u) ? bb : ~bb;
      }
      int rank = (int)__popcll(mm & ((1ull << lane) - 1ull));
      if (v && rank == 0) s.pass.wcnt[wave][d] = (unsigned)__popcll(mm);
      __syncthreads();
      // thread 'tid' scans digit 'tid' across waves; accumulate round totals
      unsigned run0 = s.pass.runCnt[tid];
      unsigned run = 0;
      #pragma unroll
      for (int w2 = 0; w2 < 4; ++w2) {
        unsigned c = s.pass.wcnt[w2][tid];
        s.pass.wcnt[w2][tid] = run0 + run;
        run += c;
      }
      s.pass.runCnt[tid] = run0 + run;
      __syncthreads();
      mykey[r] = key; mypay[r] = pay; myval[r] = v;
      mypos[r] = v ? (s.pass.wcnt[wave][d] + (unsigned)rank) : 0u;
    }
    __syncthreads();
    tileCnt[blockIdx.x * 256 + tid] = s.pass.runCnt[tid];
    gbar(ctr, 2 + 2 * p, nT);

    // per-block redundant tile prefix (<=59 coalesced loads per thread)
    unsigned baseacc = ghist[p * 256 + tid];
    for (int t = 0; t < blockIdx.x; ++t)
      baseacc += tileCnt[t * 256 + tid];
    s.pass.baseL[tid] = baseacc;
    __syncthreads();
    #pragma unroll
    for (int r = 0; r < RNDS; ++r) {
      if (myval[r]) {
        unsigned d = (mykey[r] >> shift) & 255u;
        unsigned pos = s.pass.baseL[d] + mypos[r];
        dstk[pos] = mykey[r];
        dsti[pos] = mypay[r];
      }
    }
    gbar(ctr, 3 + 2 * p, nT);
  }
  // final order in idxA (passes A->B->A->B->A)

  if (blockIdx.x != 0) return;

  // ------------------ Greedy phase (block 0, 4 waves) ----------------------
  const int T  = tnum_p[0];
  const int k0 = keep_p[0];
  const int k  = (k0 < MAXK) ? k0 : MAXK;
  const int* order = idxA;

  for (int t = tid; t < MAXT + TPAD; t += TPB) {
    s.g.tab[t] = make_int2(-1, INT_MAX);
    s.g.tabP[t] = 0xFFFF0000u;          // s2e+1 = 0, e2s_enc = 0xFFFF
  }
  if (tid == 0) s.g.gcnt = 0;
  __syncthreads();

  // two-deep prefetch, 256-wide
  int cc = -1, cs = 0, ce = 0, nc = -1;
  if (tid < N) cc = order[tid];
  if (TPB + tid < N) nc = order[TPB + tid];
  if (cc >= 0) { int2 sp = spans2[cc]; cs = sp.x; ce = sp.y; }

  int cnt = 0;
  for (int c0 = 0; c0 < N && cnt < k; c0 += TPB) {
    int pc = nc, ps = 0, pe = 0;
    if (pc >= 0) { int2 sp = spans2[pc]; ps = sp.x; pe = sp.y; }
    int i2 = c0 + 2 * TPB + tid;
    nc = (i2 < N) ? order[i2] : -1;

    // ---- parallel pre-check vs packed tables (monotone -> speculative) ----
    int w = ce - cs;
    bool crossed = false;
    #pragma unroll
    for (int off = 0; off <= MAXW; ++off) {
      unsigned tv = s.g.tabP[cs + off];
      crossed |= ((off >= 1) & (off <= w) & ((tv & 0xFFFFu) > (unsigned)(ce + 1)))
               | ((off < w) & ((tv >> 16) < (unsigned)cs));
    }
    for (int off = MAXW + 1; off <= w; ++off) {   // generic fallback (unused)
      unsigned tv = s.g.tabP[cs + off];
      crossed |= ((tv & 0xFFFFu) > (unsigned)(ce + 1));
      if (off < w) crossed |= ((tv >> 16) < (unsigned)cs);
    }
    bool ok = (cc >= 0) && !crossed;

    // ---- order-preserving survivor compression -> LDS ----
    unsigned long long bal = __ballot(ok);
    if (lane == 0) s.g.wvs[wave] = (int)__popcll(bal);
    __syncthreads();
    int wbase = 0;
    for (int w2 = 0; w2 < wave; ++w2) wbase += s.g.wvs[w2];
    int ns = s.g.wvs[0] + s.g.wvs[1] + s.g.wvs[2] + s.g.wvs[3];
    if (ok) {
      int pos = wbase + (int)__popcll(bal & ((1ull << lane) - 1ull));
      s.g.surv[pos] = ((unsigned long long)(unsigned)cs << 48)
                    | ((unsigned long long)(unsigned)ce << 32)
                    | (unsigned)cc;
    }
    __syncthreads();

    // ---- wave-0 resolution, 64 survivors at a time ----
    if (tid < 64) {
      for (int g = 0; g < ns && cnt < k; g += 64) {
        int m = ns - g; if (m > 64) m = 64;
        bool act = lane < m;
        int gs = 0, ge = 0, gc = 0;
        if (act) {
          unsigned long long pk = s.g.surv[g + lane];
          gs = (int)(pk >> 48);
          ge = (int)((pk >> 32) & 0xFFFFu);
          gc = (int)(unsigned)pk;
        }
        // re-check vs tables (captures earlier groups' in-batch updates)
        int gw = ge - gs;
        bool rc = false;
        #pragma unroll
        for (int off = 0; off <= MAXW; ++off) {
          unsigned tv = s.g.tabP[gs + off];
          rc |= ((off >= 1) & (off <= gw) & ((tv & 0xFFFFu) > (unsigned)(ge + 1)))
              | ((off < gw) & ((tv >> 16) < (unsigned)gs));
        }
        for (int off = MAXW + 1; off <= gw; ++off) {
          unsigned tv = s.g.tabP[gs + off];
          rc |= ((tv & 0xFFFFu) > (unsigned)(ge + 1));
          if (off < gw) rc |= ((tv >> 16) < (unsigned)gs);
        }
        bool pre = act && !rc;

        // 64x64 crossing matrix: C = lanes whose span crosses mine
        s.g.gsp[lane] = ((unsigned)gs << 16) | (unsigned)ge;
        __threadfence_block();
        unsigned long long C = 0;
        for (int j = 0; j < 64; ++j) {
          unsigned pj = s.g.gsp[j];                 // LDS broadcast (free)
          int sj = (int)(pj >> 16), ej = (int)(pj & 0xFFFFu);
          bool cr = (gs < sj && sj <= ge && ej > ge) ||
                    (sj < gs && gs <= ej && ej < ge);
          if (cr) C |= 1ull << j;
        }
        unsigned long long lower = (1ull << lane) - 1ull;
        unsigned long long preB = __ballot(pre);
        unsigned long long accm;
        int cnt0g = cnt;
        if (cnt + (int)__popcll(preB) <= k) {
          // bulk-accept candidates with no earlier in-group crosser
          bool easy = pre && ((C & lower) == 0ull);
          accm = __ballot(easy);
          unsigned long long rem = preB & ~accm;
          while (rem) {
            unsigned long long kmask = __ballot((C & accm & lower) != 0ull);
            int j = __ffsll((long long)rem) - 1;
            rem &= rem - 1;
            if (!((kmask >> j) & 1ull)) accm |= 1ull << j;
          }
          cnt += (int)__popcll(accm);
        } else {
          // k-cap mode: strict serial order incl. count limit
          accm = 0ull;
          unsigned long long rem = preB;
          while (rem && cnt < k) {
            unsigned long long kmask = __ballot((C & accm & lower) != 0ull);
            int j = __ffsll((long long)rem) - 1;
            rem &= rem - 1;
            if (!((kmask >> j) & 1ull)) { accm |= 1ull << j; cnt++; }
          }
        }
        bool accme = ((accm >> lane) & 1ull) != 0ull;
        if (accme) {
          int rank = (int)__popcll(accm & lower);
          s.g.acc[cnt0g + rank] =
              ((unsigned long long)(unsigned)(gs * T + ge) << 32) | (unsigned)gc;
          atomicMax(&s.g.tab[gs].x, ge);
          atomicMin(&s.g.tab[ge].y, gs);
        }
        if (accme) {      // DS ops are wave-in-order: reads see all atomics
          int2 tv = s.g.tab[gs];
          s.g.tabP[gs] = ((unsigned)(tv.y > 65535 ? 65535 : tv.y) << 16)
                       | (unsigned)(tv.x + 1);
          int2 tv2 = s.g.tab[ge];
          s.g.tabP[ge] = ((unsigned)(tv2.y > 65535 ? 65535 : tv2.y) << 16)
                       | (unsigned)(tv2.x + 1);
        }
        __threadfence_block();
      }
      if (lane == 0) s.g.gcnt = cnt;
    }
    __syncthreads();
    cnt = s.g.gcnt;
    cc = pc; cs = ps; ce = pe;
  }

  // ---- bitonic ascending sort of acc[0..cnt) by (s*T+e, cand) ----
  int M = 2;
  while (M < cnt) M <<= 1;
  for (int j = tid; j < M; j += TPB)
    if (j >= cnt) s.g.acc[j] = ~0ull;
  __syncthreads();
  for (int kk = 2; kk <= M; kk <<= 1) {
    for (int jj = kk >> 1; jj > 0; jj >>= 1) {
      for (int i3 = tid; i3 < M; i3 += TPB) {
        int ixj = i3 ^ jj;
        if (ixj > i3) {
          unsigned long long a = s.g.acc[i3], b = s.g.acc[ixj];
          bool up = ((i3 & kk) == 0);
          if ((a > b) == up) { s.g.acc[i3] = b; s.g.acc[ixj] = a; }
        }
      }
      __syncthreads();
    }
  }

  // ---- epilogue: scores | idx | spans | valid, all f32 ----
  for (int j = tid; j < k0; j += TPB) {
    if (j < cnt) {
      int cand = (int)(s.g.acc[j] & 0xFFFFFFFFu);
      out[j]                  = scores[cand];
      out[k0 + j]             = (float)cand;
      out[2 * k0 + 2 * j]     = (float)spans[2 * cand];
      out[2 * k0 + 2 * j + 1] = (float)spans[2 * cand + 1];
      out[4 * k0 + j]         = 1.0f;
    } else {
      out[j]                  = 0.0f;
      out[k0 + j]             = 0.0f;
      out[2 * k0 + 2 * j]     = 0.0f;
      out[2 * k0 + 2 * j + 1] = 0.0f;
      out[4 * k0 + j]         = 0.0f;
    }
  }
}

extern "C" void kernel_launch(void* const* d_in, const int* in_sizes, int n_in,
                              void* d_out, int out_size, void* d_ws, size_t ws_size,
                              hipStream_t stream) {
  const int*   spans  = (const int*)d_in[0];
  const float* scores = (const float*)d_in[1];
  const float* mask   = (const float*)d_in[2];
  const int*   tnum   = (const int*)d_in[3];
  const int*   keep   = (const int*)d_in[4];
  const int N = in_sizes[1];
  const int nT = (N + TILE - 1) / TILE;   // 60 for N=61440; must stay <=256

  // ws: ctr[32] | ghist[4*256] | tileCnt[nT*256] | keysA | keysB | idxA | idxB
  unsigned* ctr     = (unsigned*)d_ws;
  unsigned* ghist   = ctr + 32;
  unsigned* tileCnt = ghist + 4 * 256;
  unsigned* keysA   = tileCnt + (size_t)nT * 256;
  unsigned* keysB   = keysA + N;
  int*      idxA    = (int*)(keysB + N);
  int*      idxB    = idxA + N;
  float*    out     = (float*)d_out;

  // zero barrier counters + global histograms (re-done every replay)
  hipMemsetAsync(ctr, 0, (32 + 4 * 256) * sizeof(unsigned), stream);

  mega_kernel<<<nT, TPB, 0, stream>>>(
      (const int2*)spans, spans, scores, mask, tnum, keep, out, N, nT,
      ctr, ghist, tileCnt, keysA, keysB, idxA, idxB);
}

// Round 5
// 327.054 us; speedup vs baseline: 7.4235x; 1.1421x over previous
//
#include <hip/hip_runtime.h>
#include <math.h>
#include <limits.h>

#define TPB   256
#define TILE  1024          // items per block-tile (256 thr x 4 rounds)
#define RNDS  4
#define MAXT  2048
#define TPAD  64            // pad so unconditional reads past e stay in-bounds
#define MAXK  1024
#define MAXW  29            // max span width in this problem (W=30 -> w<=29)

// ===========================================================================
// Kernel A: fused key-build + 4-pass LSD radix argsort (60 blocks, grid bars)
// ===========================================================================
struct SortSM {
  union {
    unsigned h[4 * 256];                  // P0: 4 pass histograms
    struct {
      unsigned wcnt[4][256];              // [wave][digit] (also scan scratch)
      unsigned runCnt[256];
      unsigned baseL[256];
    } pass;
  };
};

// Device-scope grid barrier. SAFE: grid (<=60 blocks) fully co-resident on
// 256 CUs. ctr[] zeroed by memset node each launch.
__device__ inline void gbar(unsigned* ctr, int idx, unsigned nblk) {
  __syncthreads();
  if (threadIdx.x == 0) {
    __threadfence();
    atomicAdd(&ctr[idx], 1u);
    while (atomicAdd(&ctr[idx], 0u) < nblk) { __builtin_amdgcn_s_sleep(8); }
    __threadfence();
  }
  __syncthreads();
}

__global__ void __launch_bounds__(TPB, 1) sort_kernel(
    const float* __restrict__ scores, const float* __restrict__ mask,
    int N, int nT, unsigned* ctr, unsigned* ghist, unsigned* tileCnt,
    unsigned* keysA, unsigned* keysB, int* idxA, int* idxB) {
  __shared__ SortSM s;
  const int tid = threadIdx.x;
  const int lane = tid & 63;
  const int wave = tid >> 6;

  // ---- P0: build keys + all 4 histograms in one read ----
  for (int j = tid; j < 1024; j += TPB) s.h[j] = 0;
  __syncthreads();
  {
    const int tile0 = blockIdx.x * TILE;
    for (int r = 0; r < RNDS; ++r) {
      int i = tile0 + r * 256 + tid;
      if (i < N) {
        float kf = scores[i] + logf(mask[i]);          // mask==1 -> +0 exact
        unsigned u = __float_as_uint(kf);
        u = (u & 0x80000000u) ? ~u : (u | 0x80000000u);
        u = ~u;                                        // descending order
        keysA[i] = u;
        atomicAdd(&s.h[(u & 255u)], 1u);
        atomicAdd(&s.h[256 + ((u >> 8) & 255u)], 1u);
        atomicAdd(&s.h[512 + ((u >> 16) & 255u)], 1u);
        atomicAdd(&s.h[768 + (u >> 24)], 1u);
      }
    }
    __syncthreads();
    for (int j = tid; j < 1024; j += TPB)
      if (s.h[j]) atomicAdd(&ghist[j], s.h[j]);
  }
  gbar(ctr, 0, nT);

  // ---- P1: block 0 scans digit bases (4x256 exclusive) ----
  if (blockIdx.x == 0) {
    for (int p = 0; p < 4; ++p) {
      unsigned v = ghist[p * 256 + tid];
      unsigned* A = s.pass.wcnt[0];
      unsigned* B = s.pass.wcnt[1];
      A[tid] = v;
      __syncthreads();
      for (int off = 1; off < 256; off <<= 1) {
        B[tid] = A[tid] + ((tid >= off) ? A[tid - off] : 0u);
        __syncthreads();
        unsigned* t = A; A = B; B = t;
      }
      ghist[p * 256 + tid] = A[tid] - v;
      __syncthreads();
    }
  }
  gbar(ctr, 1, nT);

  // ---- 4 fused rank/scatter radix passes ----
  for (int p = 0; p < 4; ++p) {
    const unsigned* srck = (p & 1) ? keysB : keysA;
    const int*      srci = (p & 1) ? idxB : idxA;     // p==0: payload = i
    unsigned*       dstk = (p & 1) ? keysA : keysB;
    int*            dsti = (p & 1) ? idxA : idxB;
    const int shift = 8 * p;
    const int tile0 = blockIdx.x * TILE;

    s.pass.runCnt[tid] = 0;
    unsigned mykey[RNDS]; int mypay[RNDS]; unsigned mypos[RNDS]; bool myval[RNDS];
    #pragma unroll
    for (int r = 0; r < RNDS; ++r) {
      __syncthreads();
      s.pass.wcnt[0][tid] = 0; s.pass.wcnt[1][tid] = 0;
      s.pass.wcnt[2][tid] = 0; s.pass.wcnt[3][tid] = 0;
      __syncthreads();
      int i = tile0 + r * 256 + tid;
      bool v = (i < N);
      unsigned key = v ? srck[i] : 0u;
      int pay = v ? ((p == 0) ? i : srci[i]) : 0;
      unsigned d = (key >> shift) & 255u;
      unsigned long long mm = __ballot(v);     // stable rank within wave
      #pragma unroll
      for (int b = 0; b < 8; ++b) {
        unsigned long long bb = __ballot((d >> b) & 1u);
        mm &= ((d >> b) & 1u) ? bb : ~bb;
      }
      int rank = (int)__popcll(mm & ((1ull << lane) - 1ull));
      if (v && rank == 0) s.pass.wcnt[wave][d] = (unsigned)__popcll(mm);
      __syncthreads();
      unsigned run0 = s.pass.runCnt[tid];
      unsigned run = 0;
      #pragma unroll
      for (int w2 = 0; w2 < 4; ++w2) {
        unsigned c = s.pass.wcnt[w2][tid];
        s.pass.wcnt[w2][tid] = run0 + run;
        run += c;
      }
      s.pass.runCnt[tid] = run0 + run;
      __syncthreads();
      mykey[r] = key; mypay[r] = pay; myval[r] = v;
      mypos[r] = v ? (s.pass.wcnt[wave][d] + (unsigned)rank) : 0u;
    }
    __syncthreads();
    tileCnt[blockIdx.x * 256 + tid] = s.pass.runCnt[tid];
    gbar(ctr, 2 + 2 * p, nT);

    unsigned baseacc = ghist[p * 256 + tid];
    for (int t = 0; t < blockIdx.x; ++t)
      baseacc += tileCnt[t * 256 + tid];
    s.pass.baseL[tid] = baseacc;
    __syncthreads();
    #pragma unroll
    for (int r = 0; r < RNDS; ++r) {
      if (myval[r]) {
        unsigned d = (mykey[r] >> shift) & 255u;
        unsigned pos = s.pass.baseL[d] + mypos[r];
        dstk[pos] = mykey[r];
        dsti[pos] = mypay[r];
      }
    }
    if (p < 3) gbar(ctr, 3 + 2 * p, nT);
  }
  // final order in idxA (A->B->A->B->A)
}

// ===========================================================================
// Kernel B: batched-speculative greedy (1 block, 256 threads) + epilogue.
// ===========================================================================
__global__ void __launch_bounds__(TPB, 1) greedy_kernel(
    const int2* __restrict__ spans2, const int* __restrict__ spans,
    const float* __restrict__ scores, const int* __restrict__ order,
    const int* __restrict__ tnum_p, const int* __restrict__ keep_p,
    float* __restrict__ out, int N) {
  __shared__ unsigned tabP[MAXT + TPAD];  // hi16 = e2s(enc), lo16 = s2e+1
  __shared__ int2 tab[MAXT + TPAD];       // authoritative: .x=s2e, .y=e2s
  __shared__ unsigned long long acc[MAXK];
  __shared__ unsigned long long surv[TPB];
  __shared__ unsigned gsp[64];
  __shared__ int wvs[4];
  __shared__ int gcnt;

  const int tid = threadIdx.x;
  const int lane = tid & 63;
  const int wave = tid >> 6;
  const int T  = tnum_p[0];
  const int k0 = keep_p[0];
  const int k  = (k0 < MAXK) ? k0 : MAXK;

  for (int t = tid; t < MAXT + TPAD; t += TPB) {
    tab[t] = make_int2(-1, INT_MAX);
    tabP[t] = 0xFFFF0000u;               // s2e+1 = 0, e2s_enc = 0xFFFF
  }
  if (tid == 0) gcnt = 0;
  __syncthreads();

  // two-deep prefetch, 256-wide
  int cc = -1, cs = 0, ce = 0, nc = -1;
  if (tid < N) cc = order[tid];
  if (TPB + tid < N) nc = order[TPB + tid];
  if (cc >= 0) { int2 sp = spans2[cc]; cs = sp.x; ce = sp.y; }

  int cnt = 0;
  for (int c0 = 0; c0 < N && cnt < k; c0 += TPB) {
    int pc = nc, ps = 0, pe = 0;
    if (pc >= 0) { int2 sp = spans2[pc]; ps = sp.x; pe = sp.y; }
    int i2 = c0 + 2 * TPB + tid;
    nc = (i2 < N) ? order[i2] : -1;

    // ---- parallel pre-check vs packed tables (monotone -> speculative) ----
    int w = ce - cs;
    bool crossed = false;
    #pragma unroll
    for (int off = 0; off <= MAXW; ++off) {
      unsigned tv = tabP[cs + off];
      crossed |= ((off >= 1) & (off <= w) & ((tv & 0xFFFFu) > (unsigned)(ce + 1)))
               | ((off < w) & ((tv >> 16) < (unsigned)cs));
    }
    for (int off = MAXW + 1; off <= w; ++off) {   // generic fallback (unused)
      unsigned tv = tabP[cs + off];
      crossed |= ((tv & 0xFFFFu) > (unsigned)(ce + 1));
      if (off < w) crossed |= ((tv >> 16) < (unsigned)cs);
    }
    bool ok = (cc >= 0) && !crossed;

    // ---- order-preserving survivor compression -> LDS ----
    unsigned long long bal = __ballot(ok);
    if (lane == 0) wvs[wave] = (int)__popcll(bal);
    __syncthreads();
    int wbase = 0;
    for (int w2 = 0; w2 < wave; ++w2) wbase += wvs[w2];
    int ns = wvs[0] + wvs[1] + wvs[2] + wvs[3];
    if (ok) {
      int pos = wbase + (int)__popcll(bal & ((1ull << lane) - 1ull));
      surv[pos] = ((unsigned long long)(unsigned)cs << 48)
                | ((unsigned long long)(unsigned)ce << 32)
                | (unsigned)cc;
    }
    __syncthreads();

    // ---- wave-0 resolution, 64 survivors at a time ----
    if (tid < 64) {
      bool dirty = false;      // any in-batch acceptance since pre-check?
      for (int g = 0; g < ns && cnt < k; g += 64) {
        int m = ns - g; if (m > 64) m = 64;
        bool act = lane < m;
        int gs = 0, ge = 0, gc = 0;
        if (act) {
          unsigned long long pk = surv[g + lane];
          gs = (int)(pk >> 48);
          ge = (int)((pk >> 32) & 0xFFFFu);
          gc = (int)(unsigned)pk;
        }
        bool pre = act;
        if (dirty) {           // re-check only when tables changed in-batch
          int gw = ge - gs;
          bool rc = false;
          #pragma unroll
          for (int off = 0; off <= MAXW; ++off) {
            unsigned tv = tabP[gs + off];
            rc |= ((off >= 1) & (off <= gw) & ((tv & 0xFFFFu) > (unsigned)(ge + 1)))
                | ((off < gw) & ((tv >> 16) < (unsigned)gs));
          }
          for (int off = MAXW + 1; off <= gw; ++off) {
            unsigned tv = tabP[gs + off];
            rc |= ((tv & 0xFFFFu) > (unsigned)(ge + 1));
            if (off < gw) rc |= ((tv >> 16) < (unsigned)gs);
          }
          pre = act && !rc;
        }
        unsigned long long preB = __ballot(pre);
        if (preB == 0ull) continue;
        int np = (int)__popcll(preB);
        unsigned long long lower = (1ull << lane) - 1ull;
        unsigned long long accm;
        int cnt0g = cnt;
        if (np == 1) {                       // single-survivor fast path
          accm = preB;
          cnt += 1;
        } else {
          // crossing matrix limited to actual group size m
          gsp[lane] = ((unsigned)gs << 16) | (unsigned)ge;
          unsigned long long C = 0;
          for (int j = 0; j < m; ++j) {
            unsigned pj = gsp[j];            // LDS broadcast
            int sj = (int)(pj >> 16), ej = (int)(pj & 0xFFFFu);
            bool cr = (gs < sj && sj <= ge && ej > ge) ||
                      (sj < gs && gs <= ej && ej < ge);
            if (cr) C |= 1ull << j;
          }
          if (cnt + np <= k) {
            // bulk: accept all with no earlier *surviving* in-group crosser
            bool easy = pre && ((C & lower & preB) == 0ull);
            accm = __ballot(easy);
            unsigned long long rem = preB & ~accm;
            while (rem) {
              unsigned long long kmask = __ballot((C & accm & lower) != 0ull);
              int j = __ffsll((long long)rem) - 1;
              rem &= rem - 1;
              if (!((kmask >> j) & 1ull)) accm |= 1ull << j;
            }
            cnt += (int)__popcll(accm);
          } else {
            // k-cap mode: strict serial order incl. count limit
            accm = 0ull;
            unsigned long long rem = preB;
            while (rem && cnt < k) {
              unsigned long long kmask = __ballot((C & accm & lower) != 0ull);
              int j = __ffsll((long long)rem) - 1;
              rem &= rem - 1;
              if (!((kmask >> j) & 1ull)) { accm |= 1ull << j; cnt++; }
            }
          }
        }
        bool accme = ((accm >> lane) & 1ull) != 0ull;
        if (accme) {
          int rank = (int)__popcll(accm & lower);
          acc[cnt0g + rank] =
              ((unsigned long long)(unsigned)(gs * T + ge) << 32) | (unsigned)gc;
          atomicMax(&tab[gs].x, ge);
          atomicMin(&tab[ge].y, gs);
        }
        if (accme) {        // same-wave DS in-order: reads see all atomics
          int2 tv = tab[gs];
          tabP[gs] = ((unsigned)(tv.y > 65535 ? 65535 : tv.y) << 16)
                   | (unsigned)(tv.x + 1);
          int2 tv2 = tab[ge];
          tabP[ge] = ((unsigned)(tv2.y > 65535 ? 65535 : tv2.y) << 16)
                   | (unsigned)(tv2.x + 1);
        }
        if (accm) dirty = true;
      }
      if (lane == 0) gcnt = cnt;
    }
    __syncthreads();
    cnt = gcnt;
    cc = pc; cs = ps; ce = pe;
  }

  // ---- bitonic ascending sort of acc[0..cnt) by (s*T+e, cand) ----
  int M = 2;
  while (M < cnt) M <<= 1;
  for (int j = tid; j < M; j += TPB)
    if (j >= cnt) acc[j] = ~0ull;
  __syncthreads();
  for (int kk = 2; kk <= M; kk <<= 1) {
    for (int jj = kk >> 1; jj > 0; jj >>= 1) {
      for (int i3 = tid; i3 < M; i3 += TPB) {
        int ixj = i3 ^ jj;
        if (ixj > i3) {
          unsigned long long a = acc[i3], b = acc[ixj];
          bool up = ((i3 & kk) == 0);
          if ((a > b) == up) { acc[i3] = b; acc[ixj] = a; }
        }
      }
      __syncthreads();
    }
  }

  // ---- epilogue: scores | idx | spans | valid, all f32 ----
  for (int j = tid; j < k0; j += TPB) {
    if (j < cnt) {
      int cand = (int)(acc[j] & 0xFFFFFFFFu);
      out[j]                  = scores[cand];
      out[k0 + j]             = (float)cand;
      out[2 * k0 + 2 * j]     = (float)spans[2 * cand];
      out[2 * k0 + 2 * j + 1] = (float)spans[2 * cand + 1];
      out[4 * k0 + j]         = 1.0f;
    } else {
      out[j]                  = 0.0f;
      out[k0 + j]             = 0.0f;
      out[2 * k0 + 2 * j]     = 0.0f;
      out[2 * k0 + 2 * j + 1] = 0.0f;
      out[4 * k0 + j]         = 0.0f;
    }
  }
}

extern "C" void kernel_launch(void* const* d_in, const int* in_sizes, int n_in,
                              void* d_out, int out_size, void* d_ws, size_t ws_size,
                              hipStream_t stream) {
  const int*   spans  = (const int*)d_in[0];
  const float* scores = (const float*)d_in[1];
  const float* mask   = (const float*)d_in[2];
  const int*   tnum   = (const int*)d_in[3];
  const int*   keep   = (const int*)d_in[4];
  const int N = in_sizes[1];
  const int nT = (N + TILE - 1) / TILE;   // 60 for N=61440

  // ws: ctr[32] | ghist[4*256] | tileCnt[nT*256] | keysA | keysB | idxA | idxB
  unsigned* ctr     = (unsigned*)d_ws;
  unsigned* ghist   = ctr + 32;
  unsigned* tileCnt = ghist + 4 * 256;
  unsigned* keysA   = tileCnt + (size_t)nT * 256;
  unsigned* keysB   = keysA + N;
  int*      idxA    = (int*)(keysB + N);
  int*      idxB    = idxA + N;
  float*    out     = (float*)d_out;

  hipMemsetAsync(ctr, 0, (32 + 4 * 256) * sizeof(unsigned), stream);

  sort_kernel<<<nT, TPB, 0, stream>>>(scores, mask, N, nT, ctr, ghist,
                                      tileCnt, keysA, keysB, idxA, idxB);
  greedy_kernel<<<1, TPB, 0, stream>>>((const int2*)spans, spans, scores,
                                       idxA, tnum, keep, out, N);
}